// Round 10
// baseline (548.097 us; speedup 1.0000x reference)
//
#include <hip/hip_runtime.h>
#include <math.h>

#define N_NODES 20000
#define N_EDGES 640000
#define ETOT (N_EDGES + N_NODES)
#define HC 256
#define NLAYER 3
#define NBATCH 16
#define GEPS 1e-5f
#define NSLOT 64
#define L2E 1.44269504f

typedef unsigned short u16;
typedef unsigned int u32;
typedef __attribute__((ext_vector_type(8))) short short8;
typedef __attribute__((ext_vector_type(4))) float floatx4;

__device__ __forceinline__ u16 f2bf(float f) {
    u32 u = __float_as_uint(f);
    u32 r = (u + 0x7FFFu + ((u >> 16) & 1u)) >> 16;
    return (u16)r;
}

__device__ __forceinline__ float4 bf2f4(uint2 u) {
    float4 r;
    r.x = __uint_as_float(u.x << 16);
    r.y = __uint_as_float(u.x & 0xFFFF0000u);
    r.z = __uint_as_float(u.y << 16);
    r.w = __uint_as_float(u.y & 0xFFFF0000u);
    return r;
}

// VALU-only 16-lane butterfly sum
__device__ __forceinline__ float dpp_red16(float x) {
    x += __int_as_float(__builtin_amdgcn_update_dpp(0, __float_as_int(x), 0xB1, 0xF, 0xF, true));
    x += __int_as_float(__builtin_amdgcn_update_dpp(0, __float_as_int(x), 0x4E, 0xF, 0xF, true));
    x += __int_as_float(__builtin_amdgcn_update_dpp(0, __float_as_int(x), 0x141, 0xF, 0xF, true));
    x += __int_as_float(__builtin_amdgcn_update_dpp(0, __float_as_int(x), 0x140, 0xF, 0xF, true));
    return x;
}

// MFMA A/B fragment-tiled layout: buf[((rt*8 + kt)*64 + lane)*8 + j]
// where lane = (ksub>>3)*16 + (row&15), ksub = k - kt*32, j = k&7.

// ---------------- prep ----------------
// grid: [0,1250) x->tiled bf16, [1250,1634) W transpose->tiled, [1634,1754) zero

__global__ __launch_bounds__(256) void prep(const float* __restrict__ x, u16* __restrict__ xbf,
                                            const float* __restrict__ Wl, const float* __restrict__ Wr,
                                            u16* __restrict__ WT, uint4* __restrict__ zbase, int zq) {
    __shared__ float T[32][33];
    int b = blockIdx.x, tid = threadIdx.x;
    if (b < 1250) {
        int rt = b;
        int wid = tid >> 6, lane = tid & 63;
        int row = rt * 16 + (lane & 15);
        int q8 = (lane >> 4) * 8;
        #pragma unroll
        for (int kk = 0; kk < 2; ++kk) {
            int kt = wid + kk * 4;
            int kcol = kt * 32 + q8;
            const float4* px = (const float4*)(x + (size_t)row * 256 + kcol);
            float4 a = px[0], c = px[1];
            u16 o[8] = {f2bf(a.x), f2bf(a.y), f2bf(a.z), f2bf(a.w),
                        f2bf(c.x), f2bf(c.y), f2bf(c.z), f2bf(c.w)};
            *(uint4*)(xbf + (((size_t)rt * 8 + kt) * 64 + lane) * 8) = *(const uint4*)o;
        }
    } else if (b < 1634) {
        int bi = b - 1250;               // 0..383
        int kb = bi & 7;                 // k-chunk
        int nb = (bi >> 3) & 15;         // n0/32
        int l = bi >> 7;                 // layer
        int n0 = nb * 32, k0 = kb * 32;
        const float* W = ((n0 < 256) ? Wl : Wr) + (size_t)l * 65536;
        int nn0 = n0 & 255;
        int tx = tid & 31, ty = tid >> 5;
        #pragma unroll
        for (int i = 0; i < 4; ++i)
            T[ty + i * 8][tx] = W[(size_t)(k0 + ty + i * 8) * 256 + nn0 + tx];
        __syncthreads();
        int lane = tid & 63, jp = (tid >> 6) & 1, cl = tid >> 7;
        int ct = n0 / 16 + cl;
        u16 o4[4];
        #pragma unroll
        for (int jj = 0; jj < 4; ++jj)
            o4[jj] = f2bf(T[(lane >> 4) * 8 + jp * 4 + jj][cl * 16 + (lane & 15)]);
        u16* outw = WT + (size_t)l * 131072;
        *(uint2*)(outw + (((size_t)ct * 8 + kb) * 64 + lane) * 8 + jp * 4) = *(const uint2*)o4;
    } else {
        uint4 z = make_uint4(0, 0, 0, 0);
        for (int i = (b - 1634) * 256 + tid; i < zq; i += 120 * 256) zbase[i] = z;
    }
}

// ---------------- CSR build ----------------

__global__ void count_deg(const int* __restrict__ dst, int* __restrict__ deg) {
    int e = blockIdx.x * 256 + threadIdx.x;
    if (e < N_EDGES) atomicAdd(&deg[dst[e]], 1);
}

__global__ __launch_bounds__(1024) void scan_excl(int* __restrict__ data, int* __restrict__ cursor) {
    __shared__ int wsum[16];
    int t = threadIdx.x, lane = t & 63, wid = t >> 6;
    int i0 = t * 20;
    int d[20];
    int tot = 0;
    #pragma unroll
    for (int j = 0; j < 20; ++j) {
        int i = i0 + j;
        int v = (i < N_NODES) ? (data[i] + 1) : 0;
        d[j] = v;
        tot += v;
    }
    int x = tot;
    #pragma unroll
    for (int off = 1; off < 64; off <<= 1) {
        int tmp = __shfl_up(x, off);
        if (lane >= off) x += tmp;
    }
    if (lane == 63) wsum[wid] = x;
    __syncthreads();
    if (t == 0) {
        int run = 0;
        #pragma unroll
        for (int w = 0; w < 16; ++w) { int tv = wsum[w]; wsum[w] = run; run += tv; }
    }
    __syncthreads();
    int run = wsum[wid] + x - tot;
    #pragma unroll
    for (int j = 0; j < 20; ++j) {
        int i = i0 + j;
        if (i < N_NODES) { data[i] = run; cursor[i] = run; }
        run += d[j];
    }
    if (t == 0) data[N_NODES] = ETOT;
}

__global__ void scatter_edges(const int* __restrict__ src, const int* __restrict__ dst,
                              int* __restrict__ cursor, int* __restrict__ col) {
    int t = blockIdx.x * 256 + threadIdx.x;
    if (t < N_NODES) {
        int p = atomicAdd(&cursor[t], 1);
        col[p] = t;
    } else if (t < N_NODES + N_EDGES) {
        int e = t - N_NODES;
        int p = atomicAdd(&cursor[dst[e]], 1);
        col[p] = src[e];
    }
}

// ---------------- tiled-fragment bf16 MFMA GEMM: coalesced lane*16B loads ----------------
// grid (157,4): strips 0,1 -> xl; 2,3 -> xr. 4 waves x 64x64, no LDS, no barriers.

__global__ __launch_bounds__(256) void gemm_mfma(
    const u16* __restrict__ At, const u16* __restrict__ WTt,
    const float* __restrict__ b0, const float* __restrict__ b1,
    u16* __restrict__ xlb, u16* __restrict__ xrb) {
    int row0 = blockIdx.x * 128;
    int strip = blockIdx.y;
    const float* bias = (strip < 2) ? b0 : b1;
    u16* outp = (strip < 2) ? xlb : xrb;
    int c0 = (strip & 1) * 128;

    int tid = threadIdx.x;
    int wave = tid >> 6, lane = tid & 63;
    int wm = (wave & 1) * 64, wn = (wave >> 1) * 64;
    int quad = lane >> 4, l16 = lane & 15;
    int rt0 = (row0 + wm) >> 4;
    int ct0 = (strip * 128 + wn) >> 4;

    floatx4 acc[4][4] = {};
    const u16* pA[4];
    const u16* pB[4];
    #pragma unroll
    for (int mi = 0; mi < 4; ++mi) {
        int rt = min(rt0 + mi, 1249);    // clamp: junk loads, stores guarded
        pA[mi] = At + ((size_t)rt * 8) * 512 + lane * 8;
    }
    #pragma unroll
    for (int ni = 0; ni < 4; ++ni)
        pB[ni] = WTt + ((size_t)(ct0 + ni) * 8) * 512 + lane * 8;

    #pragma unroll
    for (int kt = 0; kt < 8; ++kt) {
        short8 af[4], bf[4];
        #pragma unroll
        for (int mi = 0; mi < 4; ++mi) af[mi] = *(const short8*)(pA[mi] + kt * 512);
        #pragma unroll
        for (int ni = 0; ni < 4; ++ni) bf[ni] = *(const short8*)(pB[ni] + kt * 512);
        #pragma unroll
        for (int mi = 0; mi < 4; ++mi)
            #pragma unroll
            for (int ni = 0; ni < 4; ++ni)
                acc[mi][ni] = __builtin_amdgcn_mfma_f32_16x16x32_bf16(af[mi], bf[ni], acc[mi][ni], 0, 0, 0);
    }

    // C/D layout: col = lane&15, row = quad*4 + reg
    #pragma unroll
    for (int ni = 0; ni < 4; ++ni) {
        int col = c0 + wn + ni * 16 + l16;
        float bv = bias[col];
        #pragma unroll
        for (int mi = 0; mi < 4; ++mi) {
            int gr = row0 + wm + mi * 16 + quad * 4;
            #pragma unroll
            for (int r = 0; r < 4; ++r) {
                if (gr + r < N_NODES)
                    outp[(size_t)(gr + r) * 256 + col] = f2bf(acc[mi][ni][r] + bv);
            }
        }
    }
}

// ---------------- fused GATv2 aggregation + column stats ----------------
// 512 threads = 4 nodes x 2 waves; each wave half the edge list; LDS combine.

__global__ __launch_bounds__(512) void gat_agg(
    const u16* __restrict__ xlb, const u16* __restrict__ xrb,
    const int* __restrict__ rowptr, const int* __restrict__ col,
    const float* __restrict__ att_l, const float* __restrict__ bias_l,
    u16* __restrict__ hB, float* __restrict__ slot) {
    __shared__ float pden[8][64];
    __shared__ float4 pacc[8][64];
    __shared__ float sred[4][520];
    int wid = threadIdx.x >> 6, lane = threadIdx.x & 63;
    int nw = wid >> 1, half = wid & 1;
    int node = blockIdx.x * 4 + nw;
    const uint2* xl2 = (const uint2*)xlb;
    float4 attv = ((const float4*)att_l)[lane];
    attv.x *= L2E; attv.y *= L2E; attv.z *= L2E; attv.w *= L2E;
    float4 xrv = bf2f4(((const uint2*)xrb)[(size_t)node * 64 + lane]);
    int beg = rowptr[node], end = rowptr[node + 1];
    int mid = (beg + end) >> 1;
    int j0 = half ? mid : beg;
    int j1 = half ? end : mid;

    float denom = 0.f;
    float4 acc = make_float4(0.f, 0.f, 0.f, 0.f);

    int j = j0;
    for (; j + 8 <= j1; j += 8) {
        int s[8];
        uint2 raw[8];
        float4 a[8];
        float p[8];
        #pragma unroll
        for (int u = 0; u < 8; ++u) s[u] = col[j + u];
        #pragma unroll
        for (int u = 0; u < 8; ++u) raw[u] = xl2[(size_t)s[u] * 64 + lane];
        #pragma unroll
        for (int u = 0; u < 8; ++u) {
            a[u] = bf2f4(raw[u]);
            float vx = a[u].x + xrv.x, vy = a[u].y + xrv.y;
            float vz = a[u].z + xrv.z, vw = a[u].w + xrv.w;
            vx = fmaxf(vx, 0.2f * vx);
            vy = fmaxf(vy, 0.2f * vy);
            vz = fmaxf(vz, 0.2f * vz);
            vw = fmaxf(vw, 0.2f * vw);
            p[u] = vx * attv.x + vy * attv.y + vz * attv.z + vw * attv.w;
        }
        #pragma unroll
        for (int u = 0; u < 8; ++u) p[u] = dpp_red16(p[u]);
        #pragma unroll
        for (int u = 0; u < 8; ++u) {
            float w = exp2f(p[u]);
            denom += w;
            acc.x += w * a[u].x; acc.y += w * a[u].y;
            acc.z += w * a[u].z; acc.w += w * a[u].w;
        }
    }
    for (; j < j1; ++j) {
        int s = col[j];
        float4 a = bf2f4(xl2[(size_t)s * 64 + lane]);
        float vx = a.x + xrv.x, vy = a.y + xrv.y;
        float vz = a.z + xrv.z, vw = a.w + xrv.w;
        vx = fmaxf(vx, 0.2f * vx);
        vy = fmaxf(vy, 0.2f * vy);
        vz = fmaxf(vz, 0.2f * vz);
        vw = fmaxf(vw, 0.2f * vw);
        float p = vx * attv.x + vy * attv.y + vz * attv.z + vw * attv.w;
        p = dpp_red16(p);
        float w = exp2f(p);
        denom += w;
        acc.x += w * a.x; acc.y += w * a.y; acc.z += w * a.z; acc.w += w * a.w;
    }

    if (half == 1) {
        pden[wid][lane] = denom;
        pacc[wid][lane] = acc;
    }
    __syncthreads();
    if (half == 0) {
        denom += pden[wid + 1][lane];
        float4 o2 = pacc[wid + 1][lane];
        acc.x += o2.x; acc.y += o2.y; acc.z += o2.z; acc.w += o2.w;
        float inv = 1.f / denom;
        float4 b4 = ((const float4*)bias_l)[lane];
        float4 o;
        o.x = acc.x * inv + b4.x; o.y = acc.y * inv + b4.y;
        o.z = acc.z * inv + b4.z; o.w = acc.w * inv + b4.w;
        u16 ob[4] = {f2bf(o.x), f2bf(o.y), f2bf(o.z), f2bf(o.w)};
        ((uint2*)hB)[(size_t)node * 64 + lane] = *(const uint2*)ob;
        int cb2 = lane * 4;
        sred[nw][cb2 + 0] = o.x; sred[nw][cb2 + 1] = o.y;
        sred[nw][cb2 + 2] = o.z; sred[nw][cb2 + 3] = o.w;
        sred[nw][256 + cb2 + 0] = o.x * o.x; sred[nw][256 + cb2 + 1] = o.y * o.y;
        sred[nw][256 + cb2 + 2] = o.z * o.z; sred[nw][256 + cb2 + 3] = o.w * o.w;
    }
    __syncthreads();
    int t = threadIdx.x;
    float s = sred[0][t] + sred[1][t] + sred[2][t] + sred[3][t];
    atomicAdd(&slot[(blockIdx.x & (NSLOT - 1)) * 512 + t], s);
}

// ---------------- finalize stats ----------------

__global__ __launch_bounds__(256) void fin_stats(const float* __restrict__ slot,
                                                 const float* __restrict__ nw, const float* __restrict__ nb,
                                                 const float* __restrict__ na,
                                                 float* __restrict__ wcbb) {
    int c = threadIdx.x;
    float sum = 0.f, sq = 0.f;
    for (int s = 0; s < NSLOT; ++s) {
        sum += slot[s * 512 + c];
        sq += slot[s * 512 + 256 + c];
    }
    const float invn = 1.f / (float)N_NODES;
    float mean = sum * invn, Eh2 = sq * invn;
    float a = na[c];
    float var = Eh2 - (2.f * a - a * a) * mean * mean;
    float wc = nw[c] * rsqrtf(var + GEPS);
    wcbb[c] = wc;
    wcbb[256 + c] = nb[c] - a * mean * wc;
}

// ---------------- GraphNorm + PReLU: hB(row-major bf16) -> hbf (fragment-tiled) ----------------

__global__ __launch_bounds__(256) void norm_prelu(const u16* __restrict__ hB, u16* __restrict__ hbfT,
                                                  const float* __restrict__ wcbb,
                                                  const float* __restrict__ pa, int l) {
    int rt = blockIdx.x;                 // 0..1249
    int wid = threadIdx.x >> 6, lane = threadIdx.x & 63;
    float ap = pa[l];
    int row = rt * 16 + (lane & 15);
    int q8 = (lane >> 4) * 8;
    #pragma unroll
    for (int kk = 0; kk < 2; ++kk) {
        int kt = wid + kk * 4;
        int kcol = kt * 32 + q8;
        uint4 raw = *(const uint4*)(hB + (size_t)row * 256 + kcol);
        float4 a = bf2f4(make_uint2(raw.x, raw.y));
        float4 b = bf2f4(make_uint2(raw.z, raw.w));
        float4 wc0 = *(const float4*)&wcbb[kcol];
        float4 wc1 = *(const float4*)&wcbb[kcol + 4];
        float4 bb0 = *(const float4*)&wcbb[256 + kcol];
        float4 bb1 = *(const float4*)&wcbb[256 + kcol + 4];
        a.x = a.x * wc0.x + bb0.x; a.y = a.y * wc0.y + bb0.y;
        a.z = a.z * wc0.z + bb0.z; a.w = a.w * wc0.w + bb0.w;
        b.x = b.x * wc1.x + bb1.x; b.y = b.y * wc1.y + bb1.y;
        b.z = b.z * wc1.z + bb1.z; b.w = b.w * wc1.w + bb1.w;
        a.x = fmaxf(a.x, ap * a.x); a.y = fmaxf(a.y, ap * a.y);
        a.z = fmaxf(a.z, ap * a.z); a.w = fmaxf(a.w, ap * a.w);
        b.x = fmaxf(b.x, ap * b.x); b.y = fmaxf(b.y, ap * b.y);
        b.z = fmaxf(b.z, ap * b.z); b.w = fmaxf(b.w, ap * b.w);
        u16 o[8] = {f2bf(a.x), f2bf(a.y), f2bf(a.z), f2bf(a.w),
                    f2bf(b.x), f2bf(b.y), f2bf(b.z), f2bf(b.w)};
        *(uint4*)(hbfT + (((size_t)rt * 8 + kt) * 64 + lane) * 8) = *(const uint4*)o;
    }
}

// ---------------- pool with fused final GraphNorm+PReLU ----------------

__global__ __launch_bounds__(256) void pool_kernel(const u16* __restrict__ hB,
                                                   const int* __restrict__ batch,
                                                   const float* __restrict__ slots2,
                                                   const float* __restrict__ nw, const float* __restrict__ nb,
                                                   const float* __restrict__ na, const float* __restrict__ pa,
                                                   float* __restrict__ pooled) {
    __shared__ float accs[NBATCH][256];
    int c = threadIdx.x;
    float sum = 0.f, sq = 0.f;
    for (int s = 0; s < NSLOT; ++s) {
        sum += slots2[s * 512 + c];
        sq += slots2[s * 512 + 256 + c];
    }
    const float invn = 1.f / (float)N_NODES;
    float mean = sum * invn, Eh2 = sq * invn;
    float a = na[c];
    float var = Eh2 - (2.f * a - a * a) * mean * mean;
    float wc = nw[c] * rsqrtf(var + GEPS);
    float bb = nb[c] - a * mean * wc;
    float ap = pa[2];

    #pragma unroll
    for (int b = 0; b < NBATCH; ++b) accs[b][c] = 0.f;
    int r0 = blockIdx.x * 100;
    int r1 = min(N_NODES, r0 + 100);
    for (int i = r0; i < r1; ++i) {
        float v = __uint_as_float(((u32)hB[(size_t)i * 256 + c]) << 16);
        v = v * wc + bb;
        v = fmaxf(v, ap * v);
        accs[batch[i]][c] += v;
    }
    int bmin = batch[r0], bmax = batch[r1 - 1];
    for (int b = bmin; b <= bmax; ++b) atomicAdd(&pooled[b * 256 + c], accs[b][c]);
}

// ---------------- pooled GraphNorm + FC (16 blocks) ----------------

__global__ __launch_bounds__(256) void poolnorm_fc(const float* __restrict__ pooled,
                                                   const float* __restrict__ nw, const float* __restrict__ nb,
                                                   const float* __restrict__ na,
                                                   const float* __restrict__ fcW, const float* __restrict__ fcb,
                                                   float* __restrict__ out) {
    __shared__ float pn[256];
    __shared__ float part[128];
    int b = blockIdx.x;
    int c = threadIdx.x;
    float mean = 0.f, sq = 0.f;
    #pragma unroll
    for (int i = 0; i < NBATCH; ++i) {
        float v = pooled[i * 256 + c];
        mean += v; sq += v * v;
    }
    mean *= (1.f / NBATCH); sq *= (1.f / NBATCH);
    float a = na[c];
    float var = sq - (2.f * a - a * a) * mean * mean;
    float wc = nw[c] * rsqrtf(var + GEPS);
    float bb = nb[c] - a * mean * wc;
    pn[c] = pooled[b * 256 + c] * wc + bb;
    __syncthreads();
    int o = c & 127, half = c >> 7;
    float s = 0.f;
    int kbase = half * 128;
    #pragma unroll 8
    for (int k = 0; k < 128; ++k)
        s += pn[kbase + k] * fcW[(kbase + k) * 128 + o];
    if (half == 1) part[o] = s;
    __syncthreads();
    if (half == 0) out[b * 128 + o] = s + part[o] + fcb[o];
}

// ---------------- launch ----------------

extern "C" void kernel_launch(void* const* d_in, const int* in_sizes, int n_in,
                              void* d_out, int out_size, void* d_ws, size_t ws_size,
                              hipStream_t stream) {
    const float* x    = (const float*)d_in[0];
    const int*   ei   = (const int*)d_in[1];
    const int*   batch= (const int*)d_in[2];
    const float* Wl   = (const float*)d_in[3];
    const float* bl   = (const float*)d_in[4];
    const float* Wr   = (const float*)d_in[5];
    const float* br   = (const float*)d_in[6];
    const float* att  = (const float*)d_in[7];
    const float* cb   = (const float*)d_in[8];
    const float* pa   = (const float*)d_in[9];
    const float* nw   = (const float*)d_in[10];
    const float* nb   = (const float*)d_in[11];
    const float* na   = (const float*)d_in[12];
    const float* fcW  = (const float*)d_in[13];
    const float* fcb  = (const float*)d_in[14];
    float* out = (float*)d_out;

    char* ws = (char*)d_ws;
    size_t off = 0;
    auto carve = [&](size_t bytes) -> void* {
        void* p = (void*)(ws + off);
        off += (bytes + 255) & ~(size_t)255;
        return p;
    };
    // zero-span region (prep zeroes [rowptr, end-of-pooled))
    size_t z0 = off;
    int*   rowptr = (int*)carve((N_NODES + 1) * sizeof(int));
    float* slots  = (float*)carve((size_t)NLAYER * NSLOT * 512 * sizeof(float));
    float* pooled = (float*)carve(NBATCH * HC * sizeof(float));
    size_t z1 = off;
    // non-zeroed scratch
    int*   cursor = (int*)carve(N_NODES * sizeof(int));
    int*   colidx = (int*)carve((size_t)ETOT * sizeof(int));
    u16*   xlb    = (u16*)carve((size_t)N_NODES * HC * sizeof(u16));
    u16*   xrb    = (u16*)carve((size_t)N_NODES * HC * sizeof(u16));
    u16*   hB     = (u16*)carve((size_t)N_NODES * HC * sizeof(u16));
    u16*   xbf    = (u16*)carve((size_t)N_NODES * HC * sizeof(u16));  // fragment-tiled
    u16*   hbf    = (u16*)carve((size_t)N_NODES * HC * sizeof(u16));  // fragment-tiled
    u16*   WT     = (u16*)carve((size_t)NLAYER * 512 * 256 * sizeof(u16));  // fragment-tiled
    float* wcbb   = (float*)carve(512 * sizeof(float));

    int zq = (int)((z1 - z0) / 16);
    const int* srcp = ei;
    const int* dstp = ei + N_EDGES;

    prep<<<1754, 256, 0, stream>>>(x, xbf, Wl, Wr, WT, (uint4*)(ws + z0), zq);
    count_deg<<<(N_EDGES + 255) / 256, 256, 0, stream>>>(dstp, rowptr);
    scan_excl<<<1, 1024, 0, stream>>>(rowptr, cursor);
    scatter_edges<<<(ETOT + 255) / 256, 256, 0, stream>>>(srcp, dstp, cursor, colidx);

    for (int l = 0; l < NLAYER; ++l) {
        const u16* Asrc = (l == 0) ? xbf : hbf;
        gemm_mfma<<<dim3(157, 4), 256, 0, stream>>>(Asrc, WT + (size_t)l * 131072,
                                                    bl + l * 256, br + l * 256, xlb, xrb);
        gat_agg<<<5000, 512, 0, stream>>>(xlb, xrb, rowptr, colidx, att + l * 256, cb + l * 256,
                                          hB, slots + (size_t)l * NSLOT * 512);
        if (l < NLAYER - 1) {
            fin_stats<<<1, 256, 0, stream>>>(slots + (size_t)l * NSLOT * 512, nw, nb, na, wcbb);
            norm_prelu<<<1250, 256, 0, stream>>>(hB, hbf, wcbb, pa, l);
        }
    }
    pool_kernel<<<200, 256, 0, stream>>>(hB, batch, slots + (size_t)2 * NSLOT * 512,
                                         nw, nb, na, pa, pooled);
    poolnorm_fc<<<16, 256, 0, stream>>>(pooled, nw, nb, na, fcW, fcb, out);
}

// Round 11
// 504.094 us; speedup vs baseline: 1.0873x; 1.0873x over previous
//
#include <hip/hip_runtime.h>
#include <math.h>

#define N_NODES 20000
#define N_EDGES 640000
#define ETOT (N_EDGES + N_NODES)
#define HC 256
#define NLAYER 3
#define NBATCH 16
#define GEPS 1e-5f
#define NSLOT 64
#define L2E 1.44269504f

typedef unsigned short u16;
typedef unsigned int u32;
typedef __attribute__((ext_vector_type(8))) short short8;
typedef __attribute__((ext_vector_type(4))) float floatx4;

__device__ __forceinline__ u16 f2bf(float f) {
    u32 u = __float_as_uint(f);
    u32 r = (u + 0x7FFFu + ((u >> 16) & 1u)) >> 16;
    return (u16)r;
}

__device__ __forceinline__ float4 bf2f4(uint2 u) {
    float4 r;
    r.x = __uint_as_float(u.x << 16);
    r.y = __uint_as_float(u.x & 0xFFFF0000u);
    r.z = __uint_as_float(u.y << 16);
    r.w = __uint_as_float(u.y & 0xFFFF0000u);
    return r;
}

// VALU-only 16-lane butterfly sum
__device__ __forceinline__ float dpp_red16(float x) {
    x += __int_as_float(__builtin_amdgcn_update_dpp(0, __float_as_int(x), 0xB1, 0xF, 0xF, true));
    x += __int_as_float(__builtin_amdgcn_update_dpp(0, __float_as_int(x), 0x4E, 0xF, 0xF, true));
    x += __int_as_float(__builtin_amdgcn_update_dpp(0, __float_as_int(x), 0x141, 0xF, 0xF, true));
    x += __int_as_float(__builtin_amdgcn_update_dpp(0, __float_as_int(x), 0x140, 0xF, 0xF, true));
    return x;
}

// MFMA A/B fragment-tiled layout: buf[((rt*8 + kt)*64 + lane)*8 + j]
// lane = (ksub>>3)*16 + (row&15), ksub = k - kt*32, j = k&7.

// ---------------- prep ----------------
// grid: [0,1250) x->tiled bf16, [1250,1634) W transpose->tiled, [1634,1754) zero

__global__ __launch_bounds__(256) void prep(const float* __restrict__ x, u16* __restrict__ xbf,
                                            const float* __restrict__ Wl, const float* __restrict__ Wr,
                                            u16* __restrict__ WT, uint4* __restrict__ zbase, int zq) {
    __shared__ float T[32][33];
    int b = blockIdx.x, tid = threadIdx.x;
    if (b < 1250) {
        int rt = b;
        int wid = tid >> 6, lane = tid & 63;
        int row = rt * 16 + (lane & 15);
        int q8 = (lane >> 4) * 8;
        #pragma unroll
        for (int kk = 0; kk < 2; ++kk) {
            int kt = wid + kk * 4;
            int kcol = kt * 32 + q8;
            const float4* px = (const float4*)(x + (size_t)row * 256 + kcol);
            float4 a = px[0], c = px[1];
            u16 o[8] = {f2bf(a.x), f2bf(a.y), f2bf(a.z), f2bf(a.w),
                        f2bf(c.x), f2bf(c.y), f2bf(c.z), f2bf(c.w)};
            *(uint4*)(xbf + (((size_t)rt * 8 + kt) * 64 + lane) * 8) = *(const uint4*)o;
        }
    } else if (b < 1634) {
        int bi = b - 1250;
        int kb = bi & 7;
        int nb = (bi >> 3) & 15;
        int l = bi >> 7;
        int n0 = nb * 32, k0 = kb * 32;
        const float* W = ((n0 < 256) ? Wl : Wr) + (size_t)l * 65536;
        int nn0 = n0 & 255;
        int tx = tid & 31, ty = tid >> 5;
        #pragma unroll
        for (int i = 0; i < 4; ++i)
            T[ty + i * 8][tx] = W[(size_t)(k0 + ty + i * 8) * 256 + nn0 + tx];
        __syncthreads();
        int lane = tid & 63, jp = (tid >> 6) & 1, cl = tid >> 7;
        int ct = n0 / 16 + cl;
        u16 o4[4];
        #pragma unroll
        for (int jj = 0; jj < 4; ++jj)
            o4[jj] = f2bf(T[(lane >> 4) * 8 + jp * 4 + jj][cl * 16 + (lane & 15)]);
        u16* outw = WT + (size_t)l * 131072;
        *(uint2*)(outw + (((size_t)ct * 8 + kb) * 64 + lane) * 8 + jp * 4) = *(const uint2*)o4;
    } else {
        uint4 z = make_uint4(0, 0, 0, 0);
        for (int i = (b - 1634) * 256 + tid; i < zq; i += 120 * 256) zbase[i] = z;
    }
}

// ---------------- CSR build ----------------

__global__ void count_deg(const int* __restrict__ dst, int* __restrict__ deg) {
    int e = blockIdx.x * 256 + threadIdx.x;
    if (e < N_EDGES) atomicAdd(&deg[dst[e]], 1);
}

__global__ __launch_bounds__(1024) void scan_excl(int* __restrict__ data, int* __restrict__ cursor) {
    __shared__ int wsum[16];
    int t = threadIdx.x, lane = t & 63, wid = t >> 6;
    int i0 = t * 20;
    int d[20];
    int tot = 0;
    #pragma unroll
    for (int j = 0; j < 20; ++j) {
        int i = i0 + j;
        int v = (i < N_NODES) ? (data[i] + 1) : 0;
        d[j] = v;
        tot += v;
    }
    int x = tot;
    #pragma unroll
    for (int off = 1; off < 64; off <<= 1) {
        int tmp = __shfl_up(x, off);
        if (lane >= off) x += tmp;
    }
    if (lane == 63) wsum[wid] = x;
    __syncthreads();
    if (t == 0) {
        int run = 0;
        #pragma unroll
        for (int w = 0; w < 16; ++w) { int tv = wsum[w]; wsum[w] = run; run += tv; }
    }
    __syncthreads();
    int run = wsum[wid] + x - tot;
    #pragma unroll
    for (int j = 0; j < 20; ++j) {
        int i = i0 + j;
        if (i < N_NODES) { data[i] = run; cursor[i] = run; }
        run += d[j];
    }
    if (t == 0) data[N_NODES] = ETOT;
}

__global__ void scatter_edges(const int* __restrict__ src, const int* __restrict__ dst,
                              int* __restrict__ cursor, int* __restrict__ col) {
    int t = blockIdx.x * 256 + threadIdx.x;
    if (t < N_NODES) {
        int p = atomicAdd(&cursor[t], 1);
        col[p] = t;
    } else if (t < N_NODES + N_EDGES) {
        int e = t - N_NODES;
        int p = atomicAdd(&cursor[dst[e]], 1);
        col[p] = src[e];
    }
}

// ---------------- merged-strip tiled-fragment bf16 MFMA GEMM ----------------
// grid 313: block = 64 rows x 512 cols (xl 0-255 | xr 256-511); 4 waves x (64x128).
// Tiled fragment loads (lane*16B coalesced), no K-loop barriers; LDS-staged
// coalesced epilogue (2 passes x 32 rows, stride 520 for bank spread).

__global__ __launch_bounds__(256, 1) void gemm_mfma(
    const u16* __restrict__ At, const u16* __restrict__ WTt,
    const float* __restrict__ b0, const float* __restrict__ b1,
    u16* __restrict__ xlb, u16* __restrict__ xrb) {
    __shared__ u16 tile[32][520];
    int row0 = blockIdx.x * 64;
    int tid = threadIdx.x;
    int wave = tid >> 6, lane = tid & 63;
    int quad = lane >> 4, l16 = lane & 15;
    int rt0 = row0 >> 4;
    int ct0 = wave * 8;

    floatx4 acc[4][8] = {};
    const u16* pA[4];
    const u16* pB[8];
    #pragma unroll
    for (int mi = 0; mi < 4; ++mi) {
        int rt = min(rt0 + mi, 1249);    // clamp: junk loads, stores guarded
        pA[mi] = At + (size_t)rt * 4096 + lane * 8;
    }
    #pragma unroll
    for (int ni = 0; ni < 8; ++ni)
        pB[ni] = WTt + (size_t)(ct0 + ni) * 4096 + lane * 8;

    #pragma unroll
    for (int kt = 0; kt < 8; ++kt) {
        short8 af[4], bf[8];
        #pragma unroll
        for (int mi = 0; mi < 4; ++mi) af[mi] = *(const short8*)(pA[mi] + kt * 512);
        #pragma unroll
        for (int ni = 0; ni < 8; ++ni) bf[ni] = *(const short8*)(pB[ni] + kt * 512);
        #pragma unroll
        for (int mi = 0; mi < 4; ++mi)
            #pragma unroll
            for (int ni = 0; ni < 8; ++ni)
                acc[mi][ni] = __builtin_amdgcn_mfma_f32_16x16x32_bf16(af[mi], bf[ni], acc[mi][ni], 0, 0, 0);
    }

    // bias per output column (wave*128 + ni*16 + l16 in [0,512))
    float bv[8];
    #pragma unroll
    for (int ni = 0; ni < 8; ++ni) {
        int c = wave * 128 + ni * 16 + l16;
        bv[ni] = (c < 256) ? b0[c] : b1[c - 256];
    }

    // C/D layout: col = lane&15, row = quad*4 + reg. Two passes of 32 rows.
    #pragma unroll
    for (int pass = 0; pass < 2; ++pass) {
        #pragma unroll
        for (int mi = 0; mi < 2; ++mi) {
            int lrow = mi * 16 + quad * 4;
            #pragma unroll
            for (int ni = 0; ni < 8; ++ni) {
                int c = wave * 128 + ni * 16 + l16;
                #pragma unroll
                for (int r = 0; r < 4; ++r)
                    tile[lrow + r][c] = f2bf(acc[pass * 2 + mi][ni][r] + bv[ni]);
            }
        }
        __syncthreads();
        #pragma unroll
        for (int iter = 0; iter < 8; ++iter) {
            int lrow = iter * 4 + wave;
            int gr = row0 + pass * 32 + lrow;
            if (gr < N_NODES) {
                if (lane < 32)
                    *(uint4*)(xlb + (size_t)gr * 256 + lane * 8) = *(const uint4*)&tile[lrow][lane * 8];
                else
                    *(uint4*)(xrb + (size_t)gr * 256 + (lane - 32) * 8) = *(const uint4*)&tile[lrow][256 + (lane - 32) * 8];
            }
        }
        __syncthreads();
    }
}

// ---------------- fused GATv2 aggregation + column stats ----------------
// 256 threads = 4 nodes per block; one wave per node; lane holds 4 channels.

__global__ __launch_bounds__(256) void gat_agg(
    const u16* __restrict__ xlb, const u16* __restrict__ xrb,
    const int* __restrict__ rowptr, const int* __restrict__ col,
    const float* __restrict__ att_l, const float* __restrict__ bias_l,
    u16* __restrict__ hB, float* __restrict__ slot) {
    __shared__ float sred[4][520];
    int wid = threadIdx.x >> 6, lane = threadIdx.x & 63;
    int node = blockIdx.x * 4 + wid;
    const uint2* xl2 = (const uint2*)xlb;
    float4 attv = ((const float4*)att_l)[lane];
    attv.x *= L2E; attv.y *= L2E; attv.z *= L2E; attv.w *= L2E;
    float4 xrv = bf2f4(((const uint2*)xrb)[(size_t)node * 64 + lane]);
    int beg = rowptr[node], end = rowptr[node + 1];

    float denom = 0.f;
    float4 acc = make_float4(0.f, 0.f, 0.f, 0.f);

    int j = beg;
    for (; j + 8 <= end; j += 8) {
        int s[8];
        uint2 raw[8];
        float4 a[8];
        float p[8];
        #pragma unroll
        for (int u = 0; u < 8; ++u) s[u] = col[j + u];
        #pragma unroll
        for (int u = 0; u < 8; ++u) raw[u] = xl2[(size_t)s[u] * 64 + lane];
        #pragma unroll
        for (int u = 0; u < 8; ++u) {
            a[u] = bf2f4(raw[u]);
            float vx = a[u].x + xrv.x, vy = a[u].y + xrv.y;
            float vz = a[u].z + xrv.z, vw = a[u].w + xrv.w;
            vx = fmaxf(vx, 0.2f * vx);
            vy = fmaxf(vy, 0.2f * vy);
            vz = fmaxf(vz, 0.2f * vz);
            vw = fmaxf(vw, 0.2f * vw);
            p[u] = vx * attv.x + vy * attv.y + vz * attv.z + vw * attv.w;
        }
        #pragma unroll
        for (int u = 0; u < 8; ++u) p[u] = dpp_red16(p[u]);
        #pragma unroll
        for (int u = 0; u < 8; ++u) {
            float w = exp2f(p[u]);
            denom += w;
            acc.x += w * a[u].x; acc.y += w * a[u].y;
            acc.z += w * a[u].z; acc.w += w * a[u].w;
        }
    }
    for (; j < end; ++j) {
        int s = col[j];
        float4 a = bf2f4(xl2[(size_t)s * 64 + lane]);
        float vx = a.x + xrv.x, vy = a.y + xrv.y;
        float vz = a.z + xrv.z, vw = a.w + xrv.w;
        vx = fmaxf(vx, 0.2f * vx);
        vy = fmaxf(vy, 0.2f * vy);
        vz = fmaxf(vz, 0.2f * vz);
        vw = fmaxf(vw, 0.2f * vw);
        float p = vx * attv.x + vy * attv.y + vz * attv.z + vw * attv.w;
        p = dpp_red16(p);
        float w = exp2f(p);
        denom += w;
        acc.x += w * a.x; acc.y += w * a.y; acc.z += w * a.z; acc.w += w * a.w;
    }

    float inv = 1.f / denom;
    float4 b4 = ((const float4*)bias_l)[lane];
    float4 o;
    o.x = acc.x * inv + b4.x; o.y = acc.y * inv + b4.y;
    o.z = acc.z * inv + b4.z; o.w = acc.w * inv + b4.w;
    u16 ob[4] = {f2bf(o.x), f2bf(o.y), f2bf(o.z), f2bf(o.w)};
    ((uint2*)hB)[(size_t)node * 64 + lane] = *(const uint2*)ob;

    int cb2 = lane * 4;
    sred[wid][cb2 + 0] = o.x; sred[wid][cb2 + 1] = o.y;
    sred[wid][cb2 + 2] = o.z; sred[wid][cb2 + 3] = o.w;
    sred[wid][256 + cb2 + 0] = o.x * o.x; sred[wid][256 + cb2 + 1] = o.y * o.y;
    sred[wid][256 + cb2 + 2] = o.z * o.z; sred[wid][256 + cb2 + 3] = o.w * o.w;
    __syncthreads();
    int t = threadIdx.x;
    #pragma unroll
    for (int h = 0; h < 2; ++h) {
        int idx = t + h * 256;
        float s = sred[0][idx] + sred[1][idx] + sred[2][idx] + sred[3][idx];
        atomicAdd(&slot[(blockIdx.x & (NSLOT - 1)) * 512 + idx], s);
    }
}

// ---------------- finalize stats ----------------

__global__ __launch_bounds__(256) void fin_stats(const float* __restrict__ slot,
                                                 const float* __restrict__ nw, const float* __restrict__ nb,
                                                 const float* __restrict__ na,
                                                 float* __restrict__ wcbb) {
    int c = threadIdx.x;
    float sum = 0.f, sq = 0.f;
    for (int s = 0; s < NSLOT; ++s) {
        sum += slot[s * 512 + c];
        sq += slot[s * 512 + 256 + c];
    }
    const float invn = 1.f / (float)N_NODES;
    float mean = sum * invn, Eh2 = sq * invn;
    float a = na[c];
    float var = Eh2 - (2.f * a - a * a) * mean * mean;
    float wc = nw[c] * rsqrtf(var + GEPS);
    wcbb[c] = wc;
    wcbb[256 + c] = nb[c] - a * mean * wc;
}

// ---------------- GraphNorm + PReLU: hB(row-major) -> hbf (fragment-tiled) ----------------

__global__ __launch_bounds__(256) void norm_prelu(const u16* __restrict__ hB, u16* __restrict__ hbfT,
                                                  const float* __restrict__ wcbb,
                                                  const float* __restrict__ pa, int l) {
    int rt = blockIdx.x;
    int wid = threadIdx.x >> 6, lane = threadIdx.x & 63;
    float ap = pa[l];
    int row = rt * 16 + (lane & 15);
    int q8 = (lane >> 4) * 8;
    #pragma unroll
    for (int kk = 0; kk < 2; ++kk) {
        int kt = wid + kk * 4;
        int kcol = kt * 32 + q8;
        uint4 raw = *(const uint4*)(hB + (size_t)row * 256 + kcol);
        float4 a = bf2f4(make_uint2(raw.x, raw.y));
        float4 b = bf2f4(make_uint2(raw.z, raw.w));
        float4 wc0 = *(const float4*)&wcbb[kcol];
        float4 wc1 = *(const float4*)&wcbb[kcol + 4];
        float4 bb0 = *(const float4*)&wcbb[256 + kcol];
        float4 bb1 = *(const float4*)&wcbb[256 + kcol + 4];
        a.x = a.x * wc0.x + bb0.x; a.y = a.y * wc0.y + bb0.y;
        a.z = a.z * wc0.z + bb0.z; a.w = a.w * wc0.w + bb0.w;
        b.x = b.x * wc1.x + bb1.x; b.y = b.y * wc1.y + bb1.y;
        b.z = b.z * wc1.z + bb1.z; b.w = b.w * wc1.w + bb1.w;
        a.x = fmaxf(a.x, ap * a.x); a.y = fmaxf(a.y, ap * a.y);
        a.z = fmaxf(a.z, ap * a.z); a.w = fmaxf(a.w, ap * a.w);
        b.x = fmaxf(b.x, ap * b.x); b.y = fmaxf(b.y, ap * b.y);
        b.z = fmaxf(b.z, ap * b.z); b.w = fmaxf(b.w, ap * b.w);
        u16 o[8] = {f2bf(a.x), f2bf(a.y), f2bf(a.z), f2bf(a.w),
                    f2bf(b.x), f2bf(b.y), f2bf(b.z), f2bf(b.w)};
        *(uint4*)(hbfT + (((size_t)rt * 8 + kt) * 64 + lane) * 8) = *(const uint4*)o;
    }
}

// ---------------- pool with fused final GraphNorm+PReLU ----------------

__global__ __launch_bounds__(256) void pool_kernel(const u16* __restrict__ hB,
                                                   const int* __restrict__ batch,
                                                   const float* __restrict__ slots2,
                                                   const float* __restrict__ nw, const float* __restrict__ nb,
                                                   const float* __restrict__ na, const float* __restrict__ pa,
                                                   float* __restrict__ pooled) {
    __shared__ float accs[NBATCH][256];
    int c = threadIdx.x;
    float sum = 0.f, sq = 0.f;
    for (int s = 0; s < NSLOT; ++s) {
        sum += slots2[s * 512 + c];
        sq += slots2[s * 512 + 256 + c];
    }
    const float invn = 1.f / (float)N_NODES;
    float mean = sum * invn, Eh2 = sq * invn;
    float a = na[c];
    float var = Eh2 - (2.f * a - a * a) * mean * mean;
    float wc = nw[c] * rsqrtf(var + GEPS);
    float bb = nb[c] - a * mean * wc;
    float ap = pa[2];

    #pragma unroll
    for (int b = 0; b < NBATCH; ++b) accs[b][c] = 0.f;
    int r0 = blockIdx.x * 100;
    int r1 = min(N_NODES, r0 + 100);
    for (int i = r0; i < r1; ++i) {
        float v = __uint_as_float(((u32)hB[(size_t)i * 256 + c]) << 16);
        v = v * wc + bb;
        v = fmaxf(v, ap * v);
        accs[batch[i]][c] += v;
    }
    int bmin = batch[r0], bmax = batch[r1 - 1];
    for (int b = bmin; b <= bmax; ++b) atomicAdd(&pooled[b * 256 + c], accs[b][c]);
}

// ---------------- pooled GraphNorm + FC (16 blocks) ----------------

__global__ __launch_bounds__(256) void poolnorm_fc(const float* __restrict__ pooled,
                                                   const float* __restrict__ nw, const float* __restrict__ nb,
                                                   const float* __restrict__ na,
                                                   const float* __restrict__ fcW, const float* __restrict__ fcb,
                                                   float* __restrict__ out) {
    __shared__ float pn[256];
    __shared__ float part[128];
    int b = blockIdx.x;
    int c = threadIdx.x;
    float mean = 0.f, sq = 0.f;
    #pragma unroll
    for (int i = 0; i < NBATCH; ++i) {
        float v = pooled[i * 256 + c];
        mean += v; sq += v * v;
    }
    mean *= (1.f / NBATCH); sq *= (1.f / NBATCH);
    float a = na[c];
    float var = sq - (2.f * a - a * a) * mean * mean;
    float wc = nw[c] * rsqrtf(var + GEPS);
    float bb = nb[c] - a * mean * wc;
    pn[c] = pooled[b * 256 + c] * wc + bb;
    __syncthreads();
    int o = c & 127, half = c >> 7;
    float s = 0.f;
    int kbase = half * 128;
    #pragma unroll 8
    for (int k = 0; k < 128; ++k)
        s += pn[kbase + k] * fcW[(kbase + k) * 128 + o];
    if (half == 1) part[o] = s;
    __syncthreads();
    if (half == 0) out[b * 128 + o] = s + part[o] + fcb[o];
}

// ---------------- launch ----------------

extern "C" void kernel_launch(void* const* d_in, const int* in_sizes, int n_in,
                              void* d_out, int out_size, void* d_ws, size_t ws_size,
                              hipStream_t stream) {
    const float* x    = (const float*)d_in[0];
    const int*   ei   = (const int*)d_in[1];
    const int*   batch= (const int*)d_in[2];
    const float* Wl   = (const float*)d_in[3];
    const float* bl   = (const float*)d_in[4];
    const float* Wr   = (const float*)d_in[5];
    const float* br   = (const float*)d_in[6];
    const float* att  = (const float*)d_in[7];
    const float* cb   = (const float*)d_in[8];
    const float* pa   = (const float*)d_in[9];
    const float* nw   = (const float*)d_in[10];
    const float* nb   = (const float*)d_in[11];
    const float* na   = (const float*)d_in[12];
    const float* fcW  = (const float*)d_in[13];
    const float* fcb  = (const float*)d_in[14];
    float* out = (float*)d_out;

    char* ws = (char*)d_ws;
    size_t off = 0;
    auto carve = [&](size_t bytes) -> void* {
        void* p = (void*)(ws + off);
        off += (bytes + 255) & ~(size_t)255;
        return p;
    };
    // zero-span region (prep zeroes [rowptr, end-of-pooled))
    size_t z0 = off;
    int*   rowptr = (int*)carve((N_NODES + 1) * sizeof(int));
    float* slots  = (float*)carve((size_t)NLAYER * NSLOT * 512 * sizeof(float));
    float* pooled = (float*)carve(NBATCH * HC * sizeof(float));
    size_t z1 = off;
    // non-zeroed scratch
    int*   cursor = (int*)carve(N_NODES * sizeof(int));
    int*   colidx = (int*)carve((size_t)ETOT * sizeof(int));
    u16*   xlb    = (u16*)carve((size_t)N_NODES * HC * sizeof(u16));
    u16*   xrb    = (u16*)carve((size_t)N_NODES * HC * sizeof(u16));
    u16*   hB     = (u16*)carve((size_t)N_NODES * HC * sizeof(u16));
    u16*   xbf    = (u16*)carve((size_t)N_NODES * HC * sizeof(u16));  // fragment-tiled
    u16*   hbf    = (u16*)carve((size_t)N_NODES * HC * sizeof(u16));  // fragment-tiled
    u16*   WT     = (u16*)carve((size_t)NLAYER * 512 * 256 * sizeof(u16));  // fragment-tiled
    float* wcbb   = (float*)carve(512 * sizeof(float));

    int zq = (int)((z1 - z0) / 16);
    const int* srcp = ei;
    const int* dstp = ei + N_EDGES;

    prep<<<1754, 256, 0, stream>>>(x, xbf, Wl, Wr, WT, (uint4*)(ws + z0), zq);
    count_deg<<<(N_EDGES + 255) / 256, 256, 0, stream>>>(dstp, rowptr);
    scan_excl<<<1, 1024, 0, stream>>>(rowptr, cursor);
    scatter_edges<<<(ETOT + 255) / 256, 256, 0, stream>>>(srcp, dstp, cursor, colidx);

    for (int l = 0; l < NLAYER; ++l) {
        const u16* Asrc = (l == 0) ? xbf : hbf;
        gemm_mfma<<<313, 256, 0, stream>>>(Asrc, WT + (size_t)l * 131072,
                                           bl + l * 256, br + l * 256, xlb, xrb);
        gat_agg<<<5000, 256, 0, stream>>>(xlb, xrb, rowptr, colidx, att + l * 256, cb + l * 256,
                                          hB, slots + (size_t)l * NSLOT * 512);
        if (l < NLAYER - 1) {
            fin_stats<<<1, 256, 0, stream>>>(slots + (size_t)l * NSLOT * 512, nw, nb, na, wcbb);
            norm_prelu<<<1250, 256, 0, stream>>>(hB, hbf, wcbb, pa, l);
        }
    }
    pool_kernel<<<200, 256, 0, stream>>>(hB, batch, slots + (size_t)2 * NSLOT * 512,
                                         nw, nb, na, pa, pooled);
    poolnorm_fc<<<16, 256, 0, stream>>>(pooled, nw, nb, na, fcW, fcb, out);
}

// Round 12
// 489.576 us; speedup vs baseline: 1.1195x; 1.0297x over previous
//
#include <hip/hip_runtime.h>
#include <math.h>

#define N_NODES 20000
#define N_EDGES 640000
#define ETOT (N_EDGES + N_NODES)
#define HC 256
#define NLAYER 3
#define NBATCH 16
#define GEPS 1e-5f
#define NSLOT 64
#define L2E 1.44269504f

typedef unsigned short u16;
typedef unsigned int u32;
typedef __attribute__((ext_vector_type(8))) short short8;
typedef __attribute__((ext_vector_type(4))) float floatx4;

__device__ __forceinline__ u16 f2bf(float f) {
    u32 u = __float_as_uint(f);
    u32 r = (u + 0x7FFFu + ((u >> 16) & 1u)) >> 16;
    return (u16)r;
}

__device__ __forceinline__ float4 bf2f4(uint2 u) {
    float4 r;
    r.x = __uint_as_float(u.x << 16);
    r.y = __uint_as_float(u.x & 0xFFFF0000u);
    r.z = __uint_as_float(u.y << 16);
    r.w = __uint_as_float(u.y & 0xFFFF0000u);
    return r;
}

// VALU-only 16-lane butterfly sum
__device__ __forceinline__ float dpp_red16(float x) {
    x += __int_as_float(__builtin_amdgcn_update_dpp(0, __float_as_int(x), 0xB1, 0xF, 0xF, true));
    x += __int_as_float(__builtin_amdgcn_update_dpp(0, __float_as_int(x), 0x4E, 0xF, 0xF, true));
    x += __int_as_float(__builtin_amdgcn_update_dpp(0, __float_as_int(x), 0x141, 0xF, 0xF, true));
    x += __int_as_float(__builtin_amdgcn_update_dpp(0, __float_as_int(x), 0x140, 0xF, 0xF, true));
    return x;
}

// MFMA A/B fragment-tiled layout: buf[((rt*8 + kt)*64 + lane)*8 + j]
// lane = (ksub>>3)*16 + (row&15), ksub = k - kt*32, j = k&7.

// ---------------- prep ----------------
// grid: [0,1250) x->tiled bf16, [1250,1634) W transpose->tiled, [1634,1754) zero

__global__ __launch_bounds__(256) void prep(const float* __restrict__ x, u16* __restrict__ xbf,
                                            const float* __restrict__ Wl, const float* __restrict__ Wr,
                                            u16* __restrict__ WT, uint4* __restrict__ zbase, int zq) {
    __shared__ float T[32][33];
    int b = blockIdx.x, tid = threadIdx.x;
    if (b < 1250) {
        int rt = b;
        int wid = tid >> 6, lane = tid & 63;
        int row = rt * 16 + (lane & 15);
        int q8 = (lane >> 4) * 8;
        #pragma unroll
        for (int kk = 0; kk < 2; ++kk) {
            int kt = wid + kk * 4;
            int kcol = kt * 32 + q8;
            const float4* px = (const float4*)(x + (size_t)row * 256 + kcol);
            float4 a = px[0], c = px[1];
            u16 o[8] = {f2bf(a.x), f2bf(a.y), f2bf(a.z), f2bf(a.w),
                        f2bf(c.x), f2bf(c.y), f2bf(c.z), f2bf(c.w)};
            *(uint4*)(xbf + (((size_t)rt * 8 + kt) * 64 + lane) * 8) = *(const uint4*)o;
        }
    } else if (b < 1634) {
        int bi = b - 1250;
        int kb = bi & 7;
        int nb = (bi >> 3) & 15;
        int l = bi >> 7;
        int n0 = nb * 32, k0 = kb * 32;
        const float* W = ((n0 < 256) ? Wl : Wr) + (size_t)l * 65536;
        int nn0 = n0 & 255;
        int tx = tid & 31, ty = tid >> 5;
        #pragma unroll
        for (int i = 0; i < 4; ++i)
            T[ty + i * 8][tx] = W[(size_t)(k0 + ty + i * 8) * 256 + nn0 + tx];
        __syncthreads();
        int lane = tid & 63, jp = (tid >> 6) & 1, cl = tid >> 7;
        int ct = n0 / 16 + cl;
        u16 o4[4];
        #pragma unroll
        for (int jj = 0; jj < 4; ++jj)
            o4[jj] = f2bf(T[(lane >> 4) * 8 + jp * 4 + jj][cl * 16 + (lane & 15)]);
        u16* outw = WT + (size_t)l * 131072;
        *(uint2*)(outw + (((size_t)ct * 8 + kb) * 64 + lane) * 8 + jp * 4) = *(const uint2*)o4;
    } else {
        uint4 z = make_uint4(0, 0, 0, 0);
        for (int i = (b - 1634) * 256 + tid; i < zq; i += 120 * 256) zbase[i] = z;
    }
}

// ---------------- CSR build ----------------

__global__ void count_deg(const int* __restrict__ dst, int* __restrict__ deg) {
    int e = blockIdx.x * 256 + threadIdx.x;
    if (e < N_EDGES) atomicAdd(&deg[dst[e]], 1);
}

// coalesced iterative exclusive scan of (deg+1) -> rowptr/cursor
__global__ __launch_bounds__(1024) void scan_excl(int* __restrict__ data, int* __restrict__ cursor) {
    __shared__ int wsum[16];
    __shared__ int carry_s;
    int tid = threadIdx.x, lane = tid & 63, wid = tid >> 6;
    if (tid == 0) carry_s = 0;
    __syncthreads();
    for (int base = 0; base < N_NODES; base += 1024) {
        int i = base + tid;
        int v = (i < N_NODES) ? (data[i] + 1) : 0;  // +1 = self-loop
        int x = v;
        #pragma unroll
        for (int off = 1; off < 64; off <<= 1) {
            int t = __shfl_up(x, off);
            if (lane >= off) x += t;
        }
        if (lane == 63) wsum[wid] = x;
        __syncthreads();
        int carry = carry_s;
        __syncthreads();
        if (tid == 0) {
            int run = 0;
            #pragma unroll
            for (int w2 = 0; w2 < 16; ++w2) { int t = wsum[w2]; wsum[w2] = run; run += t; }
            carry_s = carry + run;
        }
        __syncthreads();
        int excl = carry + wsum[wid] + x - v;
        if (i < N_NODES) { data[i] = excl; cursor[i] = excl; }
        __syncthreads();
    }
    if (tid == 0) data[N_NODES] = ETOT;
}

__global__ void scatter_edges(const int* __restrict__ src, const int* __restrict__ dst,
                              int* __restrict__ cursor, int* __restrict__ col) {
    int t = blockIdx.x * 256 + threadIdx.x;
    if (t < N_NODES) {
        int p = atomicAdd(&cursor[t], 1);
        col[p] = t;
    } else if (t < N_NODES + N_EDGES) {
        int e = t - N_NODES;
        int p = atomicAdd(&cursor[dst[e]], 1);
        col[p] = src[e];
    }
}

// ---------------- merged-strip tiled-fragment bf16 MFMA GEMM ----------------
// grid 313: block = 64 rows x 512 cols; 4 waves x (64x128); no K-loop barriers.
// LDS-staged coalesced epilogue.

__global__ __launch_bounds__(256, 1) void gemm_mfma(
    const u16* __restrict__ At, const u16* __restrict__ WTt,
    const float* __restrict__ b0, const float* __restrict__ b1,
    u16* __restrict__ xlb, u16* __restrict__ xrb) {
    __shared__ u16 tile[32][520];
    int row0 = blockIdx.x * 64;
    int tid = threadIdx.x;
    int wave = tid >> 6, lane = tid & 63;
    int quad = lane >> 4, l16 = lane & 15;
    int rt0 = row0 >> 4;
    int ct0 = wave * 8;

    floatx4 acc[4][8] = {};
    const u16* pA[4];
    const u16* pB[8];
    #pragma unroll
    for (int mi = 0; mi < 4; ++mi) {
        int rt = min(rt0 + mi, 1249);
        pA[mi] = At + (size_t)rt * 4096 + lane * 8;
    }
    #pragma unroll
    for (int ni = 0; ni < 8; ++ni)
        pB[ni] = WTt + (size_t)(ct0 + ni) * 4096 + lane * 8;

    #pragma unroll
    for (int kt = 0; kt < 8; ++kt) {
        short8 af[4], bf[8];
        #pragma unroll
        for (int mi = 0; mi < 4; ++mi) af[mi] = *(const short8*)(pA[mi] + kt * 512);
        #pragma unroll
        for (int ni = 0; ni < 8; ++ni) bf[ni] = *(const short8*)(pB[ni] + kt * 512);
        #pragma unroll
        for (int mi = 0; mi < 4; ++mi)
            #pragma unroll
            for (int ni = 0; ni < 8; ++ni)
                acc[mi][ni] = __builtin_amdgcn_mfma_f32_16x16x32_bf16(af[mi], bf[ni], acc[mi][ni], 0, 0, 0);
    }

    float bv[8];
    #pragma unroll
    for (int ni = 0; ni < 8; ++ni) {
        int c = wave * 128 + ni * 16 + l16;
        bv[ni] = (c < 256) ? b0[c] : b1[c - 256];
    }

    #pragma unroll
    for (int pass = 0; pass < 2; ++pass) {
        #pragma unroll
        for (int mi = 0; mi < 2; ++mi) {
            int lrow = mi * 16 + quad * 4;
            #pragma unroll
            for (int ni = 0; ni < 8; ++ni) {
                int c = wave * 128 + ni * 16 + l16;
                #pragma unroll
                for (int r = 0; r < 4; ++r)
                    tile[lrow + r][c] = f2bf(acc[pass * 2 + mi][ni][r] + bv[ni]);
            }
        }
        __syncthreads();
        #pragma unroll
        for (int iter = 0; iter < 8; ++iter) {
            int lrow = iter * 4 + wave;
            int gr = row0 + pass * 32 + lrow;
            if (gr < N_NODES) {
                if (lane < 32)
                    *(uint4*)(xlb + (size_t)gr * 256 + lane * 8) = *(const uint4*)&tile[lrow][lane * 8];
                else
                    *(uint4*)(xrb + (size_t)gr * 256 + (lane - 32) * 8) = *(const uint4*)&tile[lrow][256 + (lane - 32) * 8];
            }
        }
        __syncthreads();
    }
}

// ---------------- fused GATv2 aggregation + column stats ----------------
// 256 threads = 4 nodes per block; one wave per node; lane holds 4 channels.
// One-batch software prefetch to overlap gathers with compute.

__device__ __forceinline__ void proc8(const uint2* raw, const float4& xrv, const float4& attv,
                                      float& denom, float4& acc) {
    float4 a[8];
    float p[8];
    #pragma unroll
    for (int u = 0; u < 8; ++u) {
        a[u] = bf2f4(raw[u]);
        float vx = a[u].x + xrv.x, vy = a[u].y + xrv.y;
        float vz = a[u].z + xrv.z, vw = a[u].w + xrv.w;
        vx = fmaxf(vx, 0.2f * vx);
        vy = fmaxf(vy, 0.2f * vy);
        vz = fmaxf(vz, 0.2f * vz);
        vw = fmaxf(vw, 0.2f * vw);
        p[u] = vx * attv.x + vy * attv.y + vz * attv.z + vw * attv.w;
    }
    #pragma unroll
    for (int u = 0; u < 8; ++u) p[u] = dpp_red16(p[u]);
    #pragma unroll
    for (int u = 0; u < 8; ++u) {
        float w = exp2f(p[u]);
        denom += w;
        acc.x += w * a[u].x; acc.y += w * a[u].y;
        acc.z += w * a[u].z; acc.w += w * a[u].w;
    }
}

__global__ __launch_bounds__(256) void gat_agg(
    const u16* __restrict__ xlb, const u16* __restrict__ xrb,
    const int* __restrict__ rowptr, const int* __restrict__ col,
    const float* __restrict__ att_l, const float* __restrict__ bias_l,
    u16* __restrict__ hB, float* __restrict__ slot) {
    __shared__ float sred[4][520];
    int wid = threadIdx.x >> 6, lane = threadIdx.x & 63;
    int node = blockIdx.x * 4 + wid;
    const uint2* xl2 = (const uint2*)xlb;
    float4 attv = ((const float4*)att_l)[lane];
    attv.x *= L2E; attv.y *= L2E; attv.z *= L2E; attv.w *= L2E;
    float4 xrv = bf2f4(((const uint2*)xrb)[(size_t)node * 64 + lane]);
    int beg = rowptr[node], end = rowptr[node + 1];

    float denom = 0.f;
    float4 acc = make_float4(0.f, 0.f, 0.f, 0.f);

    int nfull = (end - beg) >> 3;
    int j = beg;
    if (nfull > 0) {
        uint2 raw[8];
        {
            int sv[8];
            #pragma unroll
            for (int u = 0; u < 8; ++u) sv[u] = col[j + u];
            #pragma unroll
            for (int u = 0; u < 8; ++u) raw[u] = xl2[(size_t)sv[u] * 64 + lane];
        }
        for (int b = 1; b < nfull; ++b) {
            int s2[8];
            uint2 raw2[8];
            #pragma unroll
            for (int u = 0; u < 8; ++u) s2[u] = col[j + 8 + u];
            #pragma unroll
            for (int u = 0; u < 8; ++u) raw2[u] = xl2[(size_t)s2[u] * 64 + lane];
            proc8(raw, xrv, attv, denom, acc);
            #pragma unroll
            for (int u = 0; u < 8; ++u) raw[u] = raw2[u];
            j += 8;
        }
        proc8(raw, xrv, attv, denom, acc);
        j += 8;
    }
    for (; j < end; ++j) {
        int s = col[j];
        float4 a = bf2f4(xl2[(size_t)s * 64 + lane]);
        float vx = a.x + xrv.x, vy = a.y + xrv.y;
        float vz = a.z + xrv.z, vw = a.w + xrv.w;
        vx = fmaxf(vx, 0.2f * vx);
        vy = fmaxf(vy, 0.2f * vy);
        vz = fmaxf(vz, 0.2f * vz);
        vw = fmaxf(vw, 0.2f * vw);
        float p = vx * attv.x + vy * attv.y + vz * attv.z + vw * attv.w;
        p = dpp_red16(p);
        float w = exp2f(p);
        denom += w;
        acc.x += w * a.x; acc.y += w * a.y; acc.z += w * a.z; acc.w += w * a.w;
    }

    float inv = 1.f / denom;
    float4 b4 = ((const float4*)bias_l)[lane];
    float4 o;
    o.x = acc.x * inv + b4.x; o.y = acc.y * inv + b4.y;
    o.z = acc.z * inv + b4.z; o.w = acc.w * inv + b4.w;
    u16 ob[4] = {f2bf(o.x), f2bf(o.y), f2bf(o.z), f2bf(o.w)};
    ((uint2*)hB)[(size_t)node * 64 + lane] = *(const uint2*)ob;

    int cb2 = lane * 4;
    sred[wid][cb2 + 0] = o.x; sred[wid][cb2 + 1] = o.y;
    sred[wid][cb2 + 2] = o.z; sred[wid][cb2 + 3] = o.w;
    sred[wid][256 + cb2 + 0] = o.x * o.x; sred[wid][256 + cb2 + 1] = o.y * o.y;
    sred[wid][256 + cb2 + 2] = o.z * o.z; sred[wid][256 + cb2 + 3] = o.w * o.w;
    __syncthreads();
    int t = threadIdx.x;
    #pragma unroll
    for (int h = 0; h < 2; ++h) {
        int idx = t + h * 256;
        float s = sred[0][idx] + sred[1][idx] + sred[2][idx] + sred[3][idx];
        atomicAdd(&slot[(blockIdx.x & (NSLOT - 1)) * 512 + idx], s);
    }
}

// ---------------- finalize stats ----------------

__global__ __launch_bounds__(256) void fin_stats(const float* __restrict__ slot,
                                                 const float* __restrict__ nw, const float* __restrict__ nb,
                                                 const float* __restrict__ na,
                                                 float* __restrict__ wcbb) {
    int c = threadIdx.x;
    float sum = 0.f, sq = 0.f;
    for (int s = 0; s < NSLOT; ++s) {
        sum += slot[s * 512 + c];
        sq += slot[s * 512 + 256 + c];
    }
    const float invn = 1.f / (float)N_NODES;
    float mean = sum * invn, Eh2 = sq * invn;
    float a = na[c];
    float var = Eh2 - (2.f * a - a * a) * mean * mean;
    float wc = nw[c] * rsqrtf(var + GEPS);
    wcbb[c] = wc;
    wcbb[256 + c] = nb[c] - a * mean * wc;
}

// ---------------- GraphNorm + PReLU: hB(row-major) -> hbf (fragment-tiled) ----------------
// LDS-staged coalesced read (16 rows x 512 B), padded stride 264 u16.

__global__ __launch_bounds__(256) void norm_prelu(const u16* __restrict__ hB, u16* __restrict__ hbfT,
                                                  const float* __restrict__ wcbb,
                                                  const float* __restrict__ pa, int l) {
    __shared__ u16 st[16 * 264];
    int rt = blockIdx.x;
    int t = threadIdx.x;
    const uint4* srcp = (const uint4*)(hB + (size_t)rt * 4096);
    #pragma unroll
    for (int h = 0; h < 2; ++h) {
        int idx = t + h * 256;           // uint4 index within 16x256 tile
        uint4 v = srcp[idx];
        int r = idx >> 5, c = (idx & 31) * 8;
        *(uint4*)&st[r * 264 + c] = v;
    }
    __syncthreads();
    int wid = t >> 6, lane = t & 63;
    float ap = pa[l];
    int rl = lane & 15;
    int q8 = (lane >> 4) * 8;
    #pragma unroll
    for (int kk = 0; kk < 2; ++kk) {
        int kt = wid + kk * 4;
        int kcol = kt * 32 + q8;
        uint4 raw = *(const uint4*)&st[rl * 264 + kcol];
        float4 a = bf2f4(make_uint2(raw.x, raw.y));
        float4 b = bf2f4(make_uint2(raw.z, raw.w));
        float4 wc0 = *(const float4*)&wcbb[kcol];
        float4 wc1 = *(const float4*)&wcbb[kcol + 4];
        float4 bb0 = *(const float4*)&wcbb[256 + kcol];
        float4 bb1 = *(const float4*)&wcbb[256 + kcol + 4];
        a.x = a.x * wc0.x + bb0.x; a.y = a.y * wc0.y + bb0.y;
        a.z = a.z * wc0.z + bb0.z; a.w = a.w * wc0.w + bb0.w;
        b.x = b.x * wc1.x + bb1.x; b.y = b.y * wc1.y + bb1.y;
        b.z = b.z * wc1.z + bb1.z; b.w = b.w * wc1.w + bb1.w;
        a.x = fmaxf(a.x, ap * a.x); a.y = fmaxf(a.y, ap * a.y);
        a.z = fmaxf(a.z, ap * a.z); a.w = fmaxf(a.w, ap * a.w);
        b.x = fmaxf(b.x, ap * b.x); b.y = fmaxf(b.y, ap * b.y);
        b.z = fmaxf(b.z, ap * b.z); b.w = fmaxf(b.w, ap * b.w);
        u16 o[8] = {f2bf(a.x), f2bf(a.y), f2bf(a.z), f2bf(a.w),
                    f2bf(b.x), f2bf(b.y), f2bf(b.z), f2bf(b.w)};
        *(uint4*)(hbfT + (((size_t)rt * 8 + kt) * 64 + lane) * 8) = *(const uint4*)o;
    }
}

// ---------------- pool with fused final GraphNorm+PReLU ----------------

__global__ __launch_bounds__(256) void pool_kernel(const u16* __restrict__ hB,
                                                   const int* __restrict__ batch,
                                                   const float* __restrict__ slots2,
                                                   const float* __restrict__ nw, const float* __restrict__ nb,
                                                   const float* __restrict__ na, const float* __restrict__ pa,
                                                   float* __restrict__ pooled) {
    __shared__ float accs[NBATCH][256];
    int c = threadIdx.x;
    float sum = 0.f, sq = 0.f;
    for (int s = 0; s < NSLOT; ++s) {
        sum += slots2[s * 512 + c];
        sq += slots2[s * 512 + 256 + c];
    }
    const float invn = 1.f / (float)N_NODES;
    float mean = sum * invn, Eh2 = sq * invn;
    float a = na[c];
    float var = Eh2 - (2.f * a - a * a) * mean * mean;
    float wc = nw[c] * rsqrtf(var + GEPS);
    float bb = nb[c] - a * mean * wc;
    float ap = pa[2];

    #pragma unroll
    for (int b = 0; b < NBATCH; ++b) accs[b][c] = 0.f;
    int r0 = blockIdx.x * 100;
    int r1 = min(N_NODES, r0 + 100);
    for (int i = r0; i < r1; ++i) {
        float v = __uint_as_float(((u32)hB[(size_t)i * 256 + c]) << 16);
        v = v * wc + bb;
        v = fmaxf(v, ap * v);
        accs[batch[i]][c] += v;
    }
    int bmin = batch[r0], bmax = batch[r1 - 1];
    for (int b = bmin; b <= bmax; ++b) atomicAdd(&pooled[b * 256 + c], accs[b][c]);
}

// ---------------- pooled GraphNorm + FC (16 blocks) ----------------

__global__ __launch_bounds__(256) void poolnorm_fc(const float* __restrict__ pooled,
                                                   const float* __restrict__ nw, const float* __restrict__ nb,
                                                   const float* __restrict__ na,
                                                   const float* __restrict__ fcW, const float* __restrict__ fcb,
                                                   float* __restrict__ out) {
    __shared__ float pn[256];
    __shared__ float part[128];
    int b = blockIdx.x;
    int c = threadIdx.x;
    float mean = 0.f, sq = 0.f;
    #pragma unroll
    for (int i = 0; i < NBATCH; ++i) {
        float v = pooled[i * 256 + c];
        mean += v; sq += v * v;
    }
    mean *= (1.f / NBATCH); sq *= (1.f / NBATCH);
    float a = na[c];
    float var = sq - (2.f * a - a * a) * mean * mean;
    float wc = nw[c] * rsqrtf(var + GEPS);
    float bb = nb[c] - a * mean * wc;
    pn[c] = pooled[b * 256 + c] * wc + bb;
    __syncthreads();
    int o = c & 127, half = c >> 7;
    float s = 0.f;
    int kbase = half * 128;
    #pragma unroll 8
    for (int k = 0; k < 128; ++k)
        s += pn[kbase + k] * fcW[(kbase + k) * 128 + o];
    if (half == 1) part[o] = s;
    __syncthreads();
    if (half == 0) out[b * 128 + o] = s + part[o] + fcb[o];
}

// ---------------- launch ----------------

extern "C" void kernel_launch(void* const* d_in, const int* in_sizes, int n_in,
                              void* d_out, int out_size, void* d_ws, size_t ws_size,
                              hipStream_t stream) {
    const float* x    = (const float*)d_in[0];
    const int*   ei   = (const int*)d_in[1];
    const int*   batch= (const int*)d_in[2];
    const float* Wl   = (const float*)d_in[3];
    const float* bl   = (const float*)d_in[4];
    const float* Wr   = (const float*)d_in[5];
    const float* br   = (const float*)d_in[6];
    const float* att  = (const float*)d_in[7];
    const float* cb   = (const float*)d_in[8];
    const float* pa   = (const float*)d_in[9];
    const float* nw   = (const float*)d_in[10];
    const float* nb   = (const float*)d_in[11];
    const float* na   = (const float*)d_in[12];
    const float* fcW  = (const float*)d_in[13];
    const float* fcb  = (const float*)d_in[14];
    float* out = (float*)d_out;

    char* ws = (char*)d_ws;
    size_t off = 0;
    auto carve = [&](size_t bytes) -> void* {
        void* p = (void*)(ws + off);
        off += (bytes + 255) & ~(size_t)255;
        return p;
    };
    // zero-span region (prep zeroes [rowptr, end-of-pooled))
    size_t z0 = off;
    int*   rowptr = (int*)carve((N_NODES + 1) * sizeof(int));
    float* slots  = (float*)carve((size_t)NLAYER * NSLOT * 512 * sizeof(float));
    float* pooled = (float*)carve(NBATCH * HC * sizeof(float));
    size_t z1 = off;
    // non-zeroed scratch
    int*   cursor = (int*)carve(N_NODES * sizeof(int));
    int*   colidx = (int*)carve((size_t)ETOT * sizeof(int));
    u16*   xlb    = (u16*)carve((size_t)N_NODES * HC * sizeof(u16));
    u16*   xrb    = (u16*)carve((size_t)N_NODES * HC * sizeof(u16));
    u16*   hB     = (u16*)carve((size_t)N_NODES * HC * sizeof(u16));
    u16*   xbf    = (u16*)carve((size_t)N_NODES * HC * sizeof(u16));  // fragment-tiled
    u16*   hbf    = (u16*)carve((size_t)N_NODES * HC * sizeof(u16));  // fragment-tiled
    u16*   WT     = (u16*)carve((size_t)NLAYER * 512 * 256 * sizeof(u16));  // fragment-tiled
    float* wcbb   = (float*)carve(512 * sizeof(float));

    int zq = (int)((z1 - z0) / 16);
    const int* srcp = ei;
    const int* dstp = ei + N_EDGES;

    prep<<<1754, 256, 0, stream>>>(x, xbf, Wl, Wr, WT, (uint4*)(ws + z0), zq);
    count_deg<<<(N_EDGES + 255) / 256, 256, 0, stream>>>(dstp, rowptr);
    scan_excl<<<1, 1024, 0, stream>>>(rowptr, cursor);
    scatter_edges<<<(ETOT + 255) / 256, 256, 0, stream>>>(srcp, dstp, cursor, colidx);

    for (int l = 0; l < NLAYER; ++l) {
        const u16* Asrc = (l == 0) ? xbf : hbf;
        gemm_mfma<<<313, 256, 0, stream>>>(Asrc, WT + (size_t)l * 131072,
                                           bl + l * 256, br + l * 256, xlb, xrb);
        gat_agg<<<5000, 256, 0, stream>>>(xlb, xrb, rowptr, colidx, att + l * 256, cb + l * 256,
                                          hB, slots + (size_t)l * NSLOT * 512);
        if (l < NLAYER - 1) {
            fin_stats<<<1, 256, 0, stream>>>(slots + (size_t)l * NSLOT * 512, nw, nb, na, wcbb);
            norm_prelu<<<1250, 256, 0, stream>>>(hB, hbf, wcbb, pa, l);
        }
    }
    pool_kernel<<<200, 256, 0, stream>>>(hB, batch, slots + (size_t)2 * NSLOT * 512,
                                         nw, nb, na, pa, pooled);
    poolnorm_fc<<<16, 256, 0, stream>>>(pooled, nw, nb, na, fcW, fcb, out);
}